// Round 5
// baseline (105.209 us; speedup 1.0000x reference)
//
#include <hip/hip_runtime.h>
#include <math.h>

// AR-GAS Student-t filter, K = 4194304 sequential steps.
// Chunked scan with burn-in (contractive map). Wall floor = (BURN+CHUNK) x
// T_chain per wave, so R5 minimizes steps/wave (CHUNK 16 + BURN 192 = 208)
// and attacks T_chain: scalar b32 LDS reads with +1-per-16 swizzle (stride
// 17 -> all 32 banks, conflict-free; uniform +17 pointer per 16-step group,
// immediate offsets), 16-deep ping-pong prefetch (LDS latency off-chain),
// 4 waves/SIMD (1024 blocks x 256 thr, 18 KB LDS, VGPR<=128).

#define CHUNK  16
#define BURN   192
#define BLOCK  256
#define OUTW   (BLOCK * CHUNK)            // 4096 outputs per block
#define REGION (OUTW + BURN)              // 4288 staged y elements
#define NG     (BURN / CHUNK)             // 12 burn groups of 16
#define SWZ(e) ((e) + ((e) >> 4))         // +1 float pad per 16
#define SY_PAD (REGION + (REGION >> 4) + 8)

__global__ __launch_bounds__(BLOCK, 4)
void ar_gas_kernel(const float* __restrict__ y,
                   const float* __restrict__ p_last_mu,
                   const float* __restrict__ p_last_s2,
                   const float* __restrict__ p_amu,
                   const float* __restrict__ p_as,
                   const float* __restrict__ p_bmu,
                   const float* __restrict__ p_bs,
                   const float* __restrict__ p_wmu,
                   const float* __restrict__ p_ws,
                   const float* __restrict__ p_nu,
                   const float* __restrict__ p_str,
                   float* __restrict__ out,
                   int n)
{
    __shared__ float sy[SY_PAD];
    const int t     = threadIdx.x;
    const int blk   = blockIdx.x;
    const int gbase = blk * OUTW - BURN;    // global index of LDS elem 0

    const float nu       = *p_nu;
    const float strength = *p_str;
    const float a_mu = (*p_amu) * strength;
    const float a_s  = (*p_as)  * strength;
    const float b_mu = *p_bmu;
    const float b_s  = *p_bs;
    const float w_mu = *p_wmu;
    const float w_s  = *p_ws;

    const float c1  = nu + 1.0f;            // scale = c1*s2 / (nu*s2 + r^2)
    const float bam = b_mu * a_mu;
    const float bas = b_s * a_s;
    const float c3  = b_s * (1.0f - a_s);

    // ---- stage y region: coalesced float4 global loads, swizzled LDS ----
    #pragma unroll
    for (int it = 0; it < 5; ++it) {
        int idx = (t + BLOCK * it) * 4;     // 4-aligned, never crosses a 16-run
        if (idx < REGION) {
            int g = gbase + idx;
            float4 v = make_float4(0.f, 0.f, 0.f, 0.f);
            if (g >= 0) v = *(const float4*)(y + g);   // block 0 pre-pad unread
            int f = SWZ(idx);
            sy[f] = v.x; sy[f + 1] = v.y; sy[f + 2] = v.z; sy[f + 3] = v.w;
        }
    }
    __syncthreads();

    // ---- initial state ----
    const bool exact = (blk == 0) && (t < NG);   // gstart < BURN
    float mu, s2;
    int e0, nG;
    if (exact) {                 // exact initial state, burn over global [0, 16t)
        mu = *p_last_mu;
        s2 = *p_last_s2;         // "last_sigma" is the variance
        e0 = BURN;               // LDS elem of global index 0
        nG = t;                  // 16t burn steps = t groups
    } else {                     // stationary guess; 192-step burn erases it
        mu = w_mu * __builtin_amdgcn_rcpf(fmaxf(1.0f - b_mu, 1e-12f));
        s2 = w_s  * __builtin_amdgcn_rcpf(fmaxf(1.0f - b_s,  1e-12f));
        e0 = t * CHUNK;
        nG = NG;
    }

#define STEP(yv) do {                                   \
        float r   = (yv) - mu;                          \
        float den = fmaf(r, r, nu * s2);                \
        float inv = __builtin_amdgcn_rcpf(den);         \
        float sr  = (c1 * s2) * inv * r;                \
        float m2  = fmaf(b_mu, mu, w_mu);               \
        float s2b = fmaf(c3, s2, w_s);                  \
        mu = fmaf(bam, sr, m2);                         \
        s2 = fmaf(bas, sr * r, s2b);                    \
    } while (0)

    // ---- burn-in: 16-step groups, ping-pong 16-deep prefetch ----
    float A[16], B[16];
    int q = SWZ(e0);                         // 16-run base -> +17 per group
    #pragma unroll
    for (int j = 0; j < 16; ++j) A[j] = sy[q + j];
    q += 17;

    int g = 0;
    while (g + 2 <= nG) {                    // nG = 12 for all but 12 lanes
        #pragma unroll
        for (int j = 0; j < 16; ++j) B[j] = sy[q + j];
        #pragma unroll
        for (int j = 0; j < 16; ++j) STEP(A[j]);
        q += 17;
        #pragma unroll
        for (int j = 0; j < 16; ++j) A[j] = sy[q + j];
        #pragma unroll
        for (int j = 0; j < 16; ++j) STEP(B[j]);
        q += 17;
        g += 2;
    }
    if (g < nG) {                            // odd nG (block-0 odd t only)
        #pragma unroll
        for (int j = 0; j < 16; ++j) B[j] = sy[q + j];
        #pragma unroll
        for (int j = 0; j < 16; ++j) STEP(A[j]);
        q += 17;
        #pragma unroll
        for (int j = 0; j < 16; ++j) A[j] = B[j];
    }
    // A now holds this thread's emit chunk (loaded pre-barrier; only the
    // owner writes those slots, so the read is safe).

    // all cross-thread burn reads must finish before in-place mu writes:
    __syncthreads();

    // ---- emit 16 steps: mu in-place over consumed y, sigma -> regs ----
    const int qe = 17 * (t + NG);            // SWZ(16*(t+NG)), uniform both paths
    float sg[16];
    #pragma unroll
    for (int j = 0; j < 16; ++j) {
        STEP(A[j]);
        sy[qe + j] = mu;
        sg[j] = __builtin_amdgcn_sqrtf(s2);
    }
#undef STEP
    __syncthreads();

    // ---- coalesced copy-out: mu ----
    const int obase = blk * OUTW;
    #pragma unroll
    for (int it = 0; it < 4; ++it) {
        int idx = (t + BLOCK * it) * 4;
        int f = SWZ(BURN + idx);             // 4 contiguous padded slots
        *(float4*)(out + obase + idx) =
            make_float4(sy[f], sy[f + 1], sy[f + 2], sy[f + 3]);
    }
    __syncthreads();

    // ---- sigma -> same LDS slots, then coalesced copy-out ----
    #pragma unroll
    for (int j = 0; j < 16; ++j) sy[qe + j] = sg[j];
    __syncthreads();
    #pragma unroll
    for (int it = 0; it < 4; ++it) {
        int idx = (t + BLOCK * it) * 4;
        int f = SWZ(BURN + idx);
        *(float4*)(out + n + obase + idx) =
            make_float4(sy[f], sy[f + 1], sy[f + 2], sy[f + 3]);
    }
}

extern "C" void kernel_launch(void* const* d_in, const int* in_sizes, int n_in,
                              void* d_out, int out_size, void* d_ws, size_t ws_size,
                              hipStream_t stream) {
    const float* y = (const float*)d_in[0];
    const int n    = in_sizes[0];              // 4194304 = 1024 * 4096
    const int grid = n / OUTW;                 // 1024 blocks

    ar_gas_kernel<<<grid, BLOCK, 0, stream>>>(
        y,
        (const float*)d_in[1],  // last_mu
        (const float*)d_in[2],  // last_sigma (variance)
        (const float*)d_in[3],  // alpha_mu
        (const float*)d_in[4],  // alpha_sigma
        (const float*)d_in[5],  // beta_mu
        (const float*)d_in[6],  // beta_sigma
        (const float*)d_in[7],  // omega_mu
        (const float*)d_in[8],  // omega_sigma
        (const float*)d_in[9],  // nu
        (const float*)d_in[10], // norm_strength
        (float*)d_out, n);
}